// Round 15
// baseline (665.734 us; speedup 1.0000x reference)
//
#include <hip/hip_runtime.h>
#include <hip/hip_fp16.h>
#include <cstdint>
#include <cstddef>

#define N_NODES 40000
#define N_EDGES 640000
#define CH 128
#define NL 3
#define NB 64
#define LN_EPS 1e-5f
#define TSTRIDE 132  // tbuf row stride (floats): 16B-aligned, conflict-free

typedef short short8 __attribute__((ext_vector_type(8)));
typedef float floatx4 __attribute__((ext_vector_type(4)));

__device__ __forceinline__ unsigned short bf16_rne(float f) {
    unsigned int u = __float_as_uint(f);
    unsigned int r = u + 0x7FFF + ((u >> 16) & 1);
    return (unsigned short)(r >> 16);
}

// ---------------------------------------------------------------- CSR build

__global__ void deg_kernel(const int* __restrict__ ei, int* __restrict__ degi) {
    int e = blockIdx.x * 256 + threadIdx.x;
    if (e < N_EDGES) atomicAdd(&degi[ei[N_EDGES + e]], 1);
}

// scan1 + isq fused
__global__ void scan1_kernel(const int* __restrict__ degi, int* __restrict__ rowptr,
                             int* __restrict__ bsum, float* __restrict__ isq) {
    __shared__ int s[256];
    int t = threadIdx.x;
    int i = blockIdx.x * 256 + t;
    int v = (i < N_NODES) ? degi[i] : 0;
    if (i < N_NODES) isq[i] = rsqrtf((float)v + 1.0f);
    s[t] = v;
    __syncthreads();
    for (int off = 1; off < 256; off <<= 1) {
        int add = (t >= off) ? s[t - off] : 0;
        __syncthreads();
        s[t] += add;
        __syncthreads();
    }
    if (i < N_NODES) rowptr[i + 1] = s[t];
    if (t == 255) bsum[blockIdx.x] = s[255];
}

__global__ void scan2_kernel(int* __restrict__ bsum, int* __restrict__ boff, int nb) {
    __shared__ int s[256];
    int t = threadIdx.x;
    int v = (t < nb) ? bsum[t] : 0;
    s[t] = v;
    __syncthreads();
    for (int off = 1; off < 256; off <<= 1) {
        int add = (t >= off) ? s[t - off] : 0;
        __syncthreads();
        s[t] += add;
        __syncthreads();
    }
    if (t < nb) boff[t] = s[t] - v;  // exclusive
}

__global__ void scan3_kernel(int* __restrict__ rowptr, const int* __restrict__ boff) {
    int i = blockIdx.x * 256 + threadIdx.x;
    if (i < N_NODES) rowptr[i + 1] += boff[blockIdx.x];
    if (i == 0 && blockIdx.x == 0) rowptr[0] = 0;
}

__global__ void fill_csr_kernel(const int* __restrict__ ei, const int* __restrict__ rowptr,
                                int* __restrict__ fill, int* __restrict__ srcs) {
    int e = blockIdx.x * 256 + threadIdx.x;
    if (e < N_EDGES) {
        int s = ei[e];
        int d = ei[N_EDGES + e];
        int pos = atomicAdd(&fill[d], 1);
        srcs[rowptr[d] + pos] = s;
    }
}

// ---------------------------------------------------------------- W packing
// Per matrix: [hi 16384 | lo 16384] bf16 shorts (64 KB). B-fragment layout for
// mfma_f32_16x16x32_bf16: frag[((kk*4+quad)*128 + n)*8 + j], k=kk*32+quad*8+j.
// bf16 split keeps lo NORMAL; fp16 split FAILED (R5/R6: lo subnormal, flushed).
__global__ void pack_w_kernel(const float* __restrict__ pre_w, const float* __restrict__ conv_w,
                              const float* __restrict__ ffn_w1, const float* __restrict__ ffn_w2,
                              short* __restrict__ wpk) {
    int idx = blockIdx.x * 256 + threadIdx.x;  // 8 * 16384 total
    int mat = idx >> 14;
    int e = idx & 16383;
    int k = e >> 7, n = e & 127;
    const float* src;
    switch (mat) {
        case 0: src = pre_w; break;
        case 1: case 2: case 3: src = conv_w + (size_t)(mat - 1) * 16384; break;
        case 4: case 5: src = ffn_w1 + (size_t)(mat - 4) * 16384; break;
        default: src = ffn_w2 + (size_t)(mat - 6) * 16384; break;
    }
    float f = src[e];
    unsigned short h = bf16_rne(f);
    float hf = __uint_as_float((unsigned)h << 16);
    unsigned short l = bf16_rne(f - hf);
    int kk = k >> 5, quad = (k >> 3) & 3, j = k & 7;
    int frag = ((kk * 4 + quad) * 128 + n) * 8 + j;
    wpk[(size_t)mat * 32768 + frag] = (short)h;
    wpk[(size_t)mat * 32768 + 16384 + frag] = (short)l;
}

// ---------------------------------------------------------------- GEMM core

__device__ __forceinline__ void gld_lds16(const short* g, short* l) {
    __builtin_amdgcn_global_load_lds(
        (const __attribute__((address_space(1))) unsigned int*)g,
        (__attribute__((address_space(3))) unsigned int*)l, 16, 0, 0);
}

// ---------------------------------------------------------------- fused multi-GEMM
// Block owns 64 rows end-to-end; intermediates pass through wave-private LDS
// tbuf (fp32, stride 132, conflict-free; each wave reads/writes only its own
// 16 rows -> no cross-wave hazard). W staged in 32 KB halves into wsm.
//
// VARIANT 0 (pre+conv0):  T = A@W1+b1 -> tbuf and fp32 OutG(H);
//                         OutC = fp16(T@W2)            [conv bias in agg]
// VARIANT 1 (FFN+conv):   T = relu(A@W1+b1) -> tbuf;
//                         Hn = LN(T@W2+b2+Res) -> tbuf and fp32 OutG(H);
//                         OutC = fp16(Hn@W3)           [next layer's conv]
template <int VARIANT>
__launch_bounds__(256, 2)
__global__ void gemm_fused(const float* __restrict__ A, const short* __restrict__ W1pk,
                           const float* __restrict__ b1, const short* __restrict__ W2pk,
                           const float* __restrict__ b2, const float* __restrict__ Res,
                           const float* __restrict__ gamma, const float* __restrict__ beta,
                           const short* __restrict__ W3pk,
                           float* __restrict__ OutG, __half* __restrict__ OutC) {
    __shared__ short wsm[16384];            // 32 KB W staging (hi|lo half)
    __shared__ float tbuf[64 * TSTRIDE];    // 33 KB wave-private rows
    const int tid = threadIdx.x;
    const int lane = tid & 63;
    const int wv = tid >> 6;
    const int row0 = blockIdx.x * 64 + wv * 16;
    const int m = lane & 15;
    const int quad = lane >> 4;

    floatx4 acc[8];
#pragma unroll
    for (int c = 0; c < 8; ++c) acc[c] = (floatx4){0.f, 0.f, 0.f, 0.f};

    const float* arow = A + (size_t)(row0 + m) * CH + quad * 8;
    float* trow_w = tbuf + (wv * 16) * TSTRIDE;             // epilogue writes
    const float* trow = tbuf + (wv * 16 + m) * TSTRIDE + quad * 8;  // A-frag reads

    // ---------------- GEMM 1: A @ W1 ----------------
#pragma unroll 1
    for (int h = 0; h < 2; ++h) {
#pragma unroll
        for (int r = 0; r < 4; ++r) {
            int off = r * 2048 + tid * 8;
            gld_lds16(W1pk + h * 8192 + off, wsm + off);
        }
#pragma unroll
        for (int r = 0; r < 4; ++r) {
            int off = r * 2048 + tid * 8;
            gld_lds16(W1pk + 16384 + h * 8192 + off, wsm + 8192 + off);
        }
        __syncthreads();

#pragma unroll 1
        for (int kx = 0; kx < 2; ++kx) {
            const int kk = h * 2 + kx;
            float4 a0 = *(const float4*)(arow + kk * 32);
            float4 a1 = *(const float4*)(arow + kk * 32 + 4);
            float av[8] = {a0.x, a0.y, a0.z, a0.w, a1.x, a1.y, a1.z, a1.w};
            short8 ahi, alo;
#pragma unroll
            for (int j = 0; j < 8; ++j) {
                unsigned short hb = bf16_rne(av[j]);
                ahi[j] = (short)hb;
                alo[j] = (short)bf16_rne(av[j] - __uint_as_float((unsigned)hb << 16));
            }
            const short* sm_h = wsm + ((kx * 4 + quad) * 128 + m) * 8;
            const short* sm_l = sm_h + 8192;
#pragma unroll
            for (int c = 0; c < 8; ++c) {
                short8 bhi = *(const short8*)(sm_h + c * 128);
                short8 blo = *(const short8*)(sm_l + c * 128);
                acc[c] = __builtin_amdgcn_mfma_f32_16x16x32_bf16(ahi, bhi, acc[c], 0, 0, 0);
                acc[c] = __builtin_amdgcn_mfma_f32_16x16x32_bf16(alo, bhi, acc[c], 0, 0, 0);
                acc[c] = __builtin_amdgcn_mfma_f32_16x16x32_bf16(ahi, blo, acc[c], 0, 0, 0);
            }
        }
        __syncthreads();
    }

    // T epilogue -> tbuf (and H to global for VARIANT 0)
#pragma unroll
    for (int c = 0; c < 8; ++c) {
        int col = c * 16 + m;
        float bv = b1[col];
#pragma unroll
        for (int r = 0; r < 4; ++r) {
            int lrow = quad * 4 + r;
            float v = acc[c][r] + bv;
            if (VARIANT == 1) v = fmaxf(v, 0.f);
            trow_w[lrow * TSTRIDE + col] = v;
            if (VARIANT == 0)
                OutG[(size_t)(row0 + quad * 4 + r) * CH + col] = v;
        }
        acc[c] = (floatx4){0.f, 0.f, 0.f, 0.f};
    }

    // ---------------- GEMM 2: T @ W2 ----------------
#pragma unroll 1
    for (int h = 0; h < 2; ++h) {
#pragma unroll
        for (int r = 0; r < 4; ++r) {
            int off = r * 2048 + tid * 8;
            gld_lds16(W2pk + h * 8192 + off, wsm + off);
        }
#pragma unroll
        for (int r = 0; r < 4; ++r) {
            int off = r * 2048 + tid * 8;
            gld_lds16(W2pk + 16384 + h * 8192 + off, wsm + 8192 + off);
        }
        __syncthreads();  // covers tbuf writes (h=0) and staging completion

#pragma unroll 1
        for (int kx = 0; kx < 2; ++kx) {
            const int kk = h * 2 + kx;
            float av[8];
#pragma unroll
            for (int j = 0; j < 8; ++j) av[j] = trow[kk * 32 + j];
            short8 ahi, alo;
#pragma unroll
            for (int j = 0; j < 8; ++j) {
                unsigned short hb = bf16_rne(av[j]);
                ahi[j] = (short)hb;
                alo[j] = (short)bf16_rne(av[j] - __uint_as_float((unsigned)hb << 16));
            }
            const short* sm_h = wsm + ((kx * 4 + quad) * 128 + m) * 8;
            const short* sm_l = sm_h + 8192;
#pragma unroll
            for (int c = 0; c < 8; ++c) {
                short8 bhi = *(const short8*)(sm_h + c * 128);
                short8 blo = *(const short8*)(sm_l + c * 128);
                acc[c] = __builtin_amdgcn_mfma_f32_16x16x32_bf16(ahi, bhi, acc[c], 0, 0, 0);
                acc[c] = __builtin_amdgcn_mfma_f32_16x16x32_bf16(alo, bhi, acc[c], 0, 0, 0);
                acc[c] = __builtin_amdgcn_mfma_f32_16x16x32_bf16(ahi, blo, acc[c], 0, 0, 0);
            }
        }
        __syncthreads();
    }

    if (VARIANT == 0) {
        // conv0 out: plain acc -> fp16 (conv bias applied in agg)
#pragma unroll
        for (int c = 0; c < 8; ++c) {
            int col = c * 16 + m;
#pragma unroll
            for (int r = 0; r < 4; ++r) {
                int row = row0 + quad * 4 + r;
                OutC[(size_t)row * CH + col] = __float2half(acc[c][r]);
            }
        }
        return;
    }

    // ---------------- FFN epilogue: LN(acc + b2 + Res) ----------------
#pragma unroll
    for (int c = 0; c < 8; ++c) {
        int col = c * 16 + m;
        float bv = b2[col];
#pragma unroll
        for (int r = 0; r < 4; ++r)
            acc[c][r] += bv + Res[(size_t)(row0 + quad * 4 + r) * CH + col];
    }
#pragma unroll
    for (int r = 0; r < 4; ++r) {
        float s = 0.f, q = 0.f;
#pragma unroll
        for (int c = 0; c < 8; ++c) {
            float t = acc[c][r];
            s += t;
            q = fmaf(t, t, q);
        }
#pragma unroll
        for (int msk = 1; msk < 16; msk <<= 1) {
            s += __shfl_xor(s, msk);
            q += __shfl_xor(q, msk);
        }
        float mean = s * (1.f / CH);
        float var = q * (1.f / CH) - mean * mean;
        float rstd = rsqrtf(var + LN_EPS);
        int row = row0 + quad * 4 + r;
        int lrow = quad * 4 + r;
#pragma unroll
        for (int c = 0; c < 8; ++c) {
            int col = c * 16 + m;
            float y = (acc[c][r] - mean) * rstd * gamma[col] + beta[col];
            OutG[(size_t)row * CH + col] = y;
            trow_w[lrow * TSTRIDE + col] = y;   // wave-private: no barrier needed
        }
    }
#pragma unroll
    for (int c = 0; c < 8; ++c) acc[c] = (floatx4){0.f, 0.f, 0.f, 0.f};

    // ---------------- GEMM 3: Hn @ W3 (next layer's conv) ----------------
#pragma unroll 1
    for (int h = 0; h < 2; ++h) {
#pragma unroll
        for (int r = 0; r < 4; ++r) {
            int off = r * 2048 + tid * 8;
            gld_lds16(W3pk + h * 8192 + off, wsm + off);
        }
#pragma unroll
        for (int r = 0; r < 4; ++r) {
            int off = r * 2048 + tid * 8;
            gld_lds16(W3pk + 16384 + h * 8192 + off, wsm + 8192 + off);
        }
        __syncthreads();

#pragma unroll 1
        for (int kx = 0; kx < 2; ++kx) {
            const int kk = h * 2 + kx;
            float av[8];
#pragma unroll
            for (int j = 0; j < 8; ++j) av[j] = trow[kk * 32 + j];
            short8 ahi, alo;
#pragma unroll
            for (int j = 0; j < 8; ++j) {
                unsigned short hb = bf16_rne(av[j]);
                ahi[j] = (short)hb;
                alo[j] = (short)bf16_rne(av[j] - __uint_as_float((unsigned)hb << 16));
            }
            const short* sm_h = wsm + ((kx * 4 + quad) * 128 + m) * 8;
            const short* sm_l = sm_h + 8192;
#pragma unroll
            for (int c = 0; c < 8; ++c) {
                short8 bhi = *(const short8*)(sm_h + c * 128);
                short8 blo = *(const short8*)(sm_l + c * 128);
                acc[c] = __builtin_amdgcn_mfma_f32_16x16x32_bf16(ahi, bhi, acc[c], 0, 0, 0);
                acc[c] = __builtin_amdgcn_mfma_f32_16x16x32_bf16(alo, bhi, acc[c], 0, 0, 0);
                acc[c] = __builtin_amdgcn_mfma_f32_16x16x32_bf16(ahi, blo, acc[c], 0, 0, 0);
            }
        }
        __syncthreads();
    }

#pragma unroll
    for (int c = 0; c < 8; ++c) {
        int col = c * 16 + m;
#pragma unroll
        for (int r = 0; r < 4; ++r) {
            int row = row0 + quad * 4 + r;
            OutC[(size_t)row * CH + col] = __float2half(acc[c][r]);
        }
    }
}

// ---------------------------------------------------------------- aggregation
// One wave per dst node, HW fp16, out fp32. 8-deep manual load prefetch
// (R10's 4-deep was the top verified win; VGPR=12 leaves huge headroom);
// fmas retired strictly in j-order (R5/R8/R9: reorder -> 7.3e-4 fail).
// FUSED=1: Hres = relu(LN(agg+bias)) + Hres.
// FUSED=2: pool-fused final layer: atomically accumulate (agg+bias) into
//          gpool[batch[node]] and count into cntf (deletes T + pool kernel;
//          pooling already used atomic fp32 adds at absmax 0).
template <int FUSED>
__launch_bounds__(256)
__global__ void agg_kernel(const __half* __restrict__ HW, const int* __restrict__ rowptr,
                           const int* __restrict__ srcs, const float* __restrict__ isq,
                           const float* __restrict__ bias, const float* __restrict__ gamma,
                           const float* __restrict__ beta, float* __restrict__ Hres,
                           const int* __restrict__ batch, float* __restrict__ gpool,
                           float* __restrict__ cntf) {
    const int lane = threadIdx.x & 63;
    const int node = blockIdx.x * 4 + (threadIdx.x >> 6);
    const int start = rowptr[node];
    const int end = rowptr[node + 1];

    float ax = 0.f, ay = 0.f;
    for (int base = start; base < end; base += 64) {
        int idx = base + lane;
        int clamped = (idx < end) ? idx : (end - 1);
        int sl = srcs[clamped];
        float wl = isq[sl];
        int cnt = end - base;
        if (cnt > 64) cnt = 64;
        int j = 0;
        for (; j + 8 <= cnt; j += 8) {
            int s[8];
            float w[8];
            float2 v[8];
#pragma unroll
            for (int q = 0; q < 8; ++q) {
                s[q] = __shfl(sl, j + q);
                w[q] = __shfl(wl, j + q);
            }
#pragma unroll
            for (int q = 0; q < 8; ++q)
                v[q] = __half22float2(*(const __half2*)(HW + (size_t)s[q] * CH + lane * 2));
#pragma unroll
            for (int q = 0; q < 8; ++q) {
                ax = fmaf(w[q], v[q].x, ax);
                ay = fmaf(w[q], v[q].y, ay);
            }
        }
        for (; j + 4 <= cnt; j += 4) {
            int s0 = __shfl(sl, j), s1 = __shfl(sl, j + 1);
            int s2 = __shfl(sl, j + 2), s3 = __shfl(sl, j + 3);
            float w0 = __shfl(wl, j), w1 = __shfl(wl, j + 1);
            float w2 = __shfl(wl, j + 2), w3 = __shfl(wl, j + 3);
            float2 v0 = __half22float2(*(const __half2*)(HW + (size_t)s0 * CH + lane * 2));
            float2 v1 = __half22float2(*(const __half2*)(HW + (size_t)s1 * CH + lane * 2));
            float2 v2 = __half22float2(*(const __half2*)(HW + (size_t)s2 * CH + lane * 2));
            float2 v3 = __half22float2(*(const __half2*)(HW + (size_t)s3 * CH + lane * 2));
            ax = fmaf(w0, v0.x, ax); ay = fmaf(w0, v0.y, ay);
            ax = fmaf(w1, v1.x, ax); ay = fmaf(w1, v1.y, ay);
            ax = fmaf(w2, v2.x, ax); ay = fmaf(w2, v2.y, ay);
            ax = fmaf(w3, v3.x, ax); ay = fmaf(w3, v3.y, ay);
        }
        for (; j < cnt; ++j) {
            int s = __shfl(sl, j);
            float w = __shfl(wl, j);
            float2 vf = __half22float2(*(const __half2*)(HW + (size_t)s * CH + lane * 2));
            ax = fmaf(w, vf.x, ax);
            ay = fmaf(w, vf.y, ay);
        }
    }
    float d = isq[node];
    const __half2 hv = *(const __half2*)(HW + (size_t)node * CH + lane * 2);
    float2 hf = __half22float2(hv);
    const float2 bb = *(const float2*)(bias + lane * 2);
    float hx = d * ax + d * d * hf.x + bb.x;
    float hy = d * ay + d * d * hf.y + bb.y;

    if (FUSED == 2) {
        int b = batch[node];
        atomicAdd(&gpool[(size_t)b * CH + lane * 2], hx);
        atomicAdd(&gpool[(size_t)b * CH + lane * 2 + 1], hy);
        if (lane == 0) atomicAdd(&cntf[b], 1.0f);
        return;
    }

    // FUSED==1: LayerNorm + ReLU + residual
    float sum = hx + hy;
    float sq = hx * hx + hy * hy;
    for (int msk = 1; msk < 64; msk <<= 1) {
        sum += __shfl_xor(sum, msk);
        sq += __shfl_xor(sq, msk);
    }
    float mean = sum * (1.f / CH);
    float var = sq * (1.f / CH) - mean * mean;
    float rstd = rsqrtf(var + LN_EPS);
    const float2 gg = *(const float2*)(gamma + lane * 2);
    const float2 be = *(const float2*)(beta + lane * 2);
    float y0 = (hx - mean) * rstd * gg.x + be.x;
    float y1 = (hy - mean) * rstd * gg.y + be.y;
    float2* hp = (float2*)(Hres + (size_t)node * CH + lane * 2);
    float2 rr = *hp;
    float2 o;
    o.x = fmaxf(y0, 0.f) + rr.x;
    o.y = fmaxf(y1, 0.f) + rr.y;
    *hp = o;
}

// ---------------------------------------------------------------- classifier
__launch_bounds__(128)
__global__ void cls_kernel(const float* __restrict__ g, const float* __restrict__ cntf,
                           const float* __restrict__ w1, const float* __restrict__ b1,
                           const float* __restrict__ w2, const float* __restrict__ b2,
                           float* __restrict__ out) {
    __shared__ float gm[CH];
    __shared__ float red[2];
    const int b = blockIdx.x;
    const int t = threadIdx.x;
    float inv = 1.f / fmaxf(cntf[b], 1.f);
    gm[t] = g[(size_t)b * CH + t] * inv;
    __syncthreads();
    float acc = b1[t];
    for (int k = 0; k < CH; ++k) acc = fmaf(gm[k], w1[(size_t)k * CH + t], acc);
    float v = fmaxf(acc, 0.f) * w2[t];
    for (int msk = 1; msk < 64; msk <<= 1) v += __shfl_xor(v, msk);
    if ((t & 63) == 0) red[t >> 6] = v;
    __syncthreads();
    if (t == 0) out[b] = red[0] + red[1] + b2[0];
}

// ---------------------------------------------------------------- launch

extern "C" void kernel_launch(void* const* d_in, const int* in_sizes, int n_in,
                              void* d_out, int out_size, void* d_ws, size_t ws_size,
                              hipStream_t stream) {
    const float* x      = (const float*)d_in[0];
    const int*   ei     = (const int*)d_in[1];
    const int*   batch  = (const int*)d_in[2];
    const float* pre_w  = (const float*)d_in[3];
    const float* pre_b  = (const float*)d_in[4];
    const float* conv_w = (const float*)d_in[5];
    const float* conv_b = (const float*)d_in[6];
    const float* ln_g   = (const float*)d_in[7];
    const float* ln_b   = (const float*)d_in[8];
    const float* ffn_w1 = (const float*)d_in[9];
    const float* ffn_b1 = (const float*)d_in[10];
    const float* ffn_w2 = (const float*)d_in[11];
    const float* ffn_b2 = (const float*)d_in[12];
    const float* fln_g  = (const float*)d_in[13];
    const float* fln_b  = (const float*)d_in[14];
    const float* cls_w1 = (const float*)d_in[15];
    const float* cls_b1 = (const float*)d_in[16];
    const float* cls_w2 = (const float*)d_in[17];
    const float* cls_b2 = (const float*)d_in[18];

    float* H    = (float*)d_ws;                       // 40000*128 f32 (residual)
    float* T    = H + (size_t)N_NODES * CH;           // (unused scratch)
    float* R    = T + (size_t)N_NODES * CH;           // scratch
    __half* HWh = (__half*)R;                         // conv out fp16 (alias)
    int*   degi = (int*)(R + (size_t)N_NODES * CH);
    int*   fill = degi + N_NODES;
    float* g    = (float*)(fill + N_NODES);           // zero zone contiguous
    float* cntf = g + (size_t)NB * CH;
    float* isq  = cntf + NB;
    int*  rowptr = (int*)(isq + N_NODES);
    int*  bsum   = rowptr + N_NODES + 1;
    int*  boff   = bsum + 256;
    int*  srcs   = boff + 256;
    short* wpk   = (short*)(srcs + N_EDGES);          // 8 x 32768 shorts

    const int nb_scan = (N_NODES + 255) / 256;  // 157

    hipMemsetAsync(degi, 0, (size_t)(2 * N_NODES + NB * CH + NB) * sizeof(int), stream);

    deg_kernel<<<N_EDGES / 256, 256, 0, stream>>>(ei, degi);
    scan1_kernel<<<nb_scan, 256, 0, stream>>>(degi, rowptr, bsum, isq);
    scan2_kernel<<<1, 256, 0, stream>>>(bsum, boff, nb_scan);
    scan3_kernel<<<nb_scan, 256, 0, stream>>>(rowptr, boff);
    fill_csr_kernel<<<N_EDGES / 256, 256, 0, stream>>>(ei, rowptr, fill, srcs);
    pack_w_kernel<<<8 * 16384 / 256, 256, 0, stream>>>(pre_w, conv_w, ffn_w1, ffn_w2, wpk);

    const int gblk = N_NODES / 64;   // 625 (exact)
    const int lblk = N_NODES / 4;    // 10000

    // fused pre-scaler + conv0: H = x@pre_w+pre_b, HWh = fp16(H@conv_w0)
    gemm_fused<0><<<gblk, 256, 0, stream>>>(x, wpk, pre_b,
                                            wpk + 1 * 32768, nullptr, nullptr,
                                            nullptr, nullptr, nullptr, H, HWh);

    for (int i = 0; i < NL; ++i) {
        if (i < NL - 1) {
            // H = relu(LN(agg(HWh)+conv_b)) + H   (fused)
            agg_kernel<1><<<lblk, 256, 0, stream>>>(HWh, rowptr, srcs, isq,
                                                    conv_b + (size_t)i * CH,
                                                    ln_g + (size_t)i * CH,
                                                    ln_b + (size_t)i * CH, H,
                                                    nullptr, nullptr, nullptr);
            // H = LN(relu(H@w1+b1)@w2+b2+H); HWh = fp16(H@conv_w[i+1])  (triple-fused)
            gemm_fused<1><<<gblk, 256, 0, stream>>>(H, wpk + (size_t)(4 + i) * 32768,
                                                    ffn_b1 + (size_t)i * CH,
                                                    wpk + (size_t)(6 + i) * 32768,
                                                    ffn_b2 + (size_t)i * CH, H,
                                                    fln_g + (size_t)i * CH,
                                                    fln_b + (size_t)i * CH,
                                                    wpk + (size_t)(2 + i) * 32768,
                                                    H, HWh);
        } else {
            // pool-fused: g[batch[n]] += agg(HWh)+conv_b, cntf[batch[n]] += 1
            agg_kernel<2><<<lblk, 256, 0, stream>>>(HWh, rowptr, srcs, isq,
                                                    conv_b + (size_t)i * CH,
                                                    nullptr, nullptr, nullptr,
                                                    batch, g, cntf);
        }
    }

    cls_kernel<<<NB, CH, 0, stream>>>(g, cntf, cls_w1, cls_b1, cls_w2, cls_b2,
                                      (float*)d_out);
}

// Round 16
// 359.304 us; speedup vs baseline: 1.8528x; 1.8528x over previous
//
#include <hip/hip_runtime.h>
#include <hip/hip_fp16.h>
#include <cstdint>
#include <cstddef>

#define N_NODES 40000
#define N_EDGES 640000
#define CH 128
#define NL 3
#define NB 64
#define LN_EPS 1e-5f
#define TSTRIDE 132  // tbuf row stride (floats): 16B-aligned, conflict-free

typedef short short8 __attribute__((ext_vector_type(8)));
typedef float floatx4 __attribute__((ext_vector_type(4)));

__device__ __forceinline__ unsigned short bf16_rne(float f) {
    unsigned int u = __float_as_uint(f);
    unsigned int r = u + 0x7FFF + ((u >> 16) & 1);
    return (unsigned short)(r >> 16);
}

// ---------------------------------------------------------------- CSR build

__global__ void deg_kernel(const int* __restrict__ ei, int* __restrict__ degi) {
    int e = blockIdx.x * 256 + threadIdx.x;
    if (e < N_EDGES) atomicAdd(&degi[ei[N_EDGES + e]], 1);
}

// scan1 + isq fused
__global__ void scan1_kernel(const int* __restrict__ degi, int* __restrict__ rowptr,
                             int* __restrict__ bsum, float* __restrict__ isq) {
    __shared__ int s[256];
    int t = threadIdx.x;
    int i = blockIdx.x * 256 + t;
    int v = (i < N_NODES) ? degi[i] : 0;
    if (i < N_NODES) isq[i] = rsqrtf((float)v + 1.0f);
    s[t] = v;
    __syncthreads();
    for (int off = 1; off < 256; off <<= 1) {
        int add = (t >= off) ? s[t - off] : 0;
        __syncthreads();
        s[t] += add;
        __syncthreads();
    }
    if (i < N_NODES) rowptr[i + 1] = s[t];
    if (t == 255) bsum[blockIdx.x] = s[255];
}

__global__ void scan2_kernel(int* __restrict__ bsum, int* __restrict__ boff, int nb) {
    __shared__ int s[256];
    int t = threadIdx.x;
    int v = (t < nb) ? bsum[t] : 0;
    s[t] = v;
    __syncthreads();
    for (int off = 1; off < 256; off <<= 1) {
        int add = (t >= off) ? s[t - off] : 0;
        __syncthreads();
        s[t] += add;
        __syncthreads();
    }
    if (t < nb) boff[t] = s[t] - v;  // exclusive
}

__global__ void scan3_kernel(int* __restrict__ rowptr, const int* __restrict__ boff) {
    int i = blockIdx.x * 256 + threadIdx.x;
    if (i < N_NODES) rowptr[i + 1] += boff[blockIdx.x];
    if (i == 0 && blockIdx.x == 0) rowptr[0] = 0;
}

__global__ void fill_csr_kernel(const int* __restrict__ ei, const int* __restrict__ rowptr,
                                int* __restrict__ fill, int* __restrict__ srcs) {
    int e = blockIdx.x * 256 + threadIdx.x;
    if (e < N_EDGES) {
        int s = ei[e];
        int d = ei[N_EDGES + e];
        int pos = atomicAdd(&fill[d], 1);
        srcs[rowptr[d] + pos] = s;
    }
}

// ---------------------------------------------------------------- W packing
// Per matrix: [hi 16384 | lo 16384] bf16 shorts (64 KB). B-fragment layout for
// mfma_f32_16x16x32_bf16: frag[((kk*4+quad)*128 + n)*8 + j], k=kk*32+quad*8+j.
// bf16 split keeps lo NORMAL; fp16 split FAILED (R5/R6: lo subnormal, flushed).
__global__ void pack_w_kernel(const float* __restrict__ pre_w, const float* __restrict__ conv_w,
                              const float* __restrict__ ffn_w1, const float* __restrict__ ffn_w2,
                              short* __restrict__ wpk) {
    int idx = blockIdx.x * 256 + threadIdx.x;  // 8 * 16384 total
    int mat = idx >> 14;
    int e = idx & 16383;
    int k = e >> 7, n = e & 127;
    const float* src;
    switch (mat) {
        case 0: src = pre_w; break;
        case 1: case 2: case 3: src = conv_w + (size_t)(mat - 1) * 16384; break;
        case 4: case 5: src = ffn_w1 + (size_t)(mat - 4) * 16384; break;
        default: src = ffn_w2 + (size_t)(mat - 6) * 16384; break;
    }
    float f = src[e];
    unsigned short h = bf16_rne(f);
    float hf = __uint_as_float((unsigned)h << 16);
    unsigned short l = bf16_rne(f - hf);
    int kk = k >> 5, quad = (k >> 3) & 3, j = k & 7;
    int frag = ((kk * 4 + quad) * 128 + n) * 8 + j;
    wpk[(size_t)mat * 32768 + frag] = (short)h;
    wpk[(size_t)mat * 32768 + 16384 + frag] = (short)l;
}

// ---------------------------------------------------------------- GEMM core

__device__ __forceinline__ void gld_lds16(const short* g, short* l) {
    __builtin_amdgcn_global_load_lds(
        (const __attribute__((address_space(1))) unsigned int*)g,
        (__attribute__((address_space(3))) unsigned int*)l, 16, 0, 0);
}

// ---------------------------------------------------------------- fused multi-GEMM
// Block owns 64 rows end-to-end; intermediates pass through wave-private LDS
// tbuf (fp32, stride 132, conflict-free; each wave reads/writes only its own
// 16 rows -> no cross-wave hazard). W staged in 32 KB halves into wsm.
//
// VARIANT 0 (pre+conv0):  T = A@W1+b1 -> tbuf and fp32 OutG(H);
//                         OutC = fp16(T@W2)            [conv bias in agg]
// VARIANT 1 (FFN+conv):   T = relu(A@W1+b1) -> tbuf;
//                         Hn = LN(T@W2+b2+Res) -> tbuf and fp32 OutG(H);
//                         OutC = fp16(Hn@W3)           [next layer's conv]
template <int VARIANT>
__launch_bounds__(256, 2)
__global__ void gemm_fused(const float* __restrict__ A, const short* __restrict__ W1pk,
                           const float* __restrict__ b1, const short* __restrict__ W2pk,
                           const float* __restrict__ b2, const float* __restrict__ Res,
                           const float* __restrict__ gamma, const float* __restrict__ beta,
                           const short* __restrict__ W3pk,
                           float* __restrict__ OutG, __half* __restrict__ OutC) {
    __shared__ short wsm[16384];            // 32 KB W staging (hi|lo half)
    __shared__ float tbuf[64 * TSTRIDE];    // 33 KB wave-private rows
    const int tid = threadIdx.x;
    const int lane = tid & 63;
    const int wv = tid >> 6;
    const int row0 = blockIdx.x * 64 + wv * 16;
    const int m = lane & 15;
    const int quad = lane >> 4;

    floatx4 acc[8];
#pragma unroll
    for (int c = 0; c < 8; ++c) acc[c] = (floatx4){0.f, 0.f, 0.f, 0.f};

    const float* arow = A + (size_t)(row0 + m) * CH + quad * 8;
    float* trow_w = tbuf + (wv * 16) * TSTRIDE;             // epilogue writes
    const float* trow = tbuf + (wv * 16 + m) * TSTRIDE + quad * 8;  // A-frag reads

    // ---------------- GEMM 1: A @ W1 ----------------
#pragma unroll 1
    for (int h = 0; h < 2; ++h) {
#pragma unroll
        for (int r = 0; r < 4; ++r) {
            int off = r * 2048 + tid * 8;
            gld_lds16(W1pk + h * 8192 + off, wsm + off);
        }
#pragma unroll
        for (int r = 0; r < 4; ++r) {
            int off = r * 2048 + tid * 8;
            gld_lds16(W1pk + 16384 + h * 8192 + off, wsm + 8192 + off);
        }
        __syncthreads();

#pragma unroll 1
        for (int kx = 0; kx < 2; ++kx) {
            const int kk = h * 2 + kx;
            float4 a0 = *(const float4*)(arow + kk * 32);
            float4 a1 = *(const float4*)(arow + kk * 32 + 4);
            float av[8] = {a0.x, a0.y, a0.z, a0.w, a1.x, a1.y, a1.z, a1.w};
            short8 ahi, alo;
#pragma unroll
            for (int j = 0; j < 8; ++j) {
                unsigned short hb = bf16_rne(av[j]);
                ahi[j] = (short)hb;
                alo[j] = (short)bf16_rne(av[j] - __uint_as_float((unsigned)hb << 16));
            }
            const short* sm_h = wsm + ((kx * 4 + quad) * 128 + m) * 8;
            const short* sm_l = sm_h + 8192;
#pragma unroll
            for (int c = 0; c < 8; ++c) {
                short8 bhi = *(const short8*)(sm_h + c * 128);
                short8 blo = *(const short8*)(sm_l + c * 128);
                acc[c] = __builtin_amdgcn_mfma_f32_16x16x32_bf16(ahi, bhi, acc[c], 0, 0, 0);
                acc[c] = __builtin_amdgcn_mfma_f32_16x16x32_bf16(alo, bhi, acc[c], 0, 0, 0);
                acc[c] = __builtin_amdgcn_mfma_f32_16x16x32_bf16(ahi, blo, acc[c], 0, 0, 0);
            }
        }
        __syncthreads();
    }

    // T epilogue -> tbuf (and H to global for VARIANT 0)
#pragma unroll
    for (int c = 0; c < 8; ++c) {
        int col = c * 16 + m;
        float bv = b1[col];
#pragma unroll
        for (int r = 0; r < 4; ++r) {
            int lrow = quad * 4 + r;
            float v = acc[c][r] + bv;
            if (VARIANT == 1) v = fmaxf(v, 0.f);
            trow_w[lrow * TSTRIDE + col] = v;
            if (VARIANT == 0)
                OutG[(size_t)(row0 + quad * 4 + r) * CH + col] = v;
        }
        acc[c] = (floatx4){0.f, 0.f, 0.f, 0.f};
    }

    // ---------------- GEMM 2: T @ W2 ----------------
#pragma unroll 1
    for (int h = 0; h < 2; ++h) {
#pragma unroll
        for (int r = 0; r < 4; ++r) {
            int off = r * 2048 + tid * 8;
            gld_lds16(W2pk + h * 8192 + off, wsm + off);
        }
#pragma unroll
        for (int r = 0; r < 4; ++r) {
            int off = r * 2048 + tid * 8;
            gld_lds16(W2pk + 16384 + h * 8192 + off, wsm + 8192 + off);
        }
        __syncthreads();  // covers tbuf writes (h=0) and staging completion

#pragma unroll 1
        for (int kx = 0; kx < 2; ++kx) {
            const int kk = h * 2 + kx;
            float av[8];
#pragma unroll
            for (int j = 0; j < 8; ++j) av[j] = trow[kk * 32 + j];
            short8 ahi, alo;
#pragma unroll
            for (int j = 0; j < 8; ++j) {
                unsigned short hb = bf16_rne(av[j]);
                ahi[j] = (short)hb;
                alo[j] = (short)bf16_rne(av[j] - __uint_as_float((unsigned)hb << 16));
            }
            const short* sm_h = wsm + ((kx * 4 + quad) * 128 + m) * 8;
            const short* sm_l = sm_h + 8192;
#pragma unroll
            for (int c = 0; c < 8; ++c) {
                short8 bhi = *(const short8*)(sm_h + c * 128);
                short8 blo = *(const short8*)(sm_l + c * 128);
                acc[c] = __builtin_amdgcn_mfma_f32_16x16x32_bf16(ahi, bhi, acc[c], 0, 0, 0);
                acc[c] = __builtin_amdgcn_mfma_f32_16x16x32_bf16(alo, bhi, acc[c], 0, 0, 0);
                acc[c] = __builtin_amdgcn_mfma_f32_16x16x32_bf16(ahi, blo, acc[c], 0, 0, 0);
            }
        }
        __syncthreads();
    }

    if (VARIANT == 0) {
        // conv0 out: plain acc -> fp16 (conv bias applied in agg)
#pragma unroll
        for (int c = 0; c < 8; ++c) {
            int col = c * 16 + m;
#pragma unroll
            for (int r = 0; r < 4; ++r) {
                int row = row0 + quad * 4 + r;
                OutC[(size_t)row * CH + col] = __float2half(acc[c][r]);
            }
        }
        return;
    }

    // ---------------- FFN epilogue: LN(acc + b2 + Res) ----------------
#pragma unroll
    for (int c = 0; c < 8; ++c) {
        int col = c * 16 + m;
        float bv = b2[col];
#pragma unroll
        for (int r = 0; r < 4; ++r)
            acc[c][r] += bv + Res[(size_t)(row0 + quad * 4 + r) * CH + col];
    }
#pragma unroll
    for (int r = 0; r < 4; ++r) {
        float s = 0.f, q = 0.f;
#pragma unroll
        for (int c = 0; c < 8; ++c) {
            float t = acc[c][r];
            s += t;
            q = fmaf(t, t, q);
        }
#pragma unroll
        for (int msk = 1; msk < 16; msk <<= 1) {
            s += __shfl_xor(s, msk);
            q += __shfl_xor(q, msk);
        }
        float mean = s * (1.f / CH);
        float var = q * (1.f / CH) - mean * mean;
        float rstd = rsqrtf(var + LN_EPS);
        int row = row0 + quad * 4 + r;
        int lrow = quad * 4 + r;
#pragma unroll
        for (int c = 0; c < 8; ++c) {
            int col = c * 16 + m;
            float y = (acc[c][r] - mean) * rstd * gamma[col] + beta[col];
            OutG[(size_t)row * CH + col] = y;
            trow_w[lrow * TSTRIDE + col] = y;   // wave-private: no barrier needed
        }
    }
#pragma unroll
    for (int c = 0; c < 8; ++c) acc[c] = (floatx4){0.f, 0.f, 0.f, 0.f};

    // ---------------- GEMM 3: Hn @ W3 (next layer's conv) ----------------
#pragma unroll 1
    for (int h = 0; h < 2; ++h) {
#pragma unroll
        for (int r = 0; r < 4; ++r) {
            int off = r * 2048 + tid * 8;
            gld_lds16(W3pk + h * 8192 + off, wsm + off);
        }
#pragma unroll
        for (int r = 0; r < 4; ++r) {
            int off = r * 2048 + tid * 8;
            gld_lds16(W3pk + 16384 + h * 8192 + off, wsm + 8192 + off);
        }
        __syncthreads();

#pragma unroll 1
        for (int kx = 0; kx < 2; ++kx) {
            const int kk = h * 2 + kx;
            float av[8];
#pragma unroll
            for (int j = 0; j < 8; ++j) av[j] = trow[kk * 32 + j];
            short8 ahi, alo;
#pragma unroll
            for (int j = 0; j < 8; ++j) {
                unsigned short hb = bf16_rne(av[j]);
                ahi[j] = (short)hb;
                alo[j] = (short)bf16_rne(av[j] - __uint_as_float((unsigned)hb << 16));
            }
            const short* sm_h = wsm + ((kx * 4 + quad) * 128 + m) * 8;
            const short* sm_l = sm_h + 8192;
#pragma unroll
            for (int c = 0; c < 8; ++c) {
                short8 bhi = *(const short8*)(sm_h + c * 128);
                short8 blo = *(const short8*)(sm_l + c * 128);
                acc[c] = __builtin_amdgcn_mfma_f32_16x16x32_bf16(ahi, bhi, acc[c], 0, 0, 0);
                acc[c] = __builtin_amdgcn_mfma_f32_16x16x32_bf16(alo, bhi, acc[c], 0, 0, 0);
                acc[c] = __builtin_amdgcn_mfma_f32_16x16x32_bf16(ahi, blo, acc[c], 0, 0, 0);
            }
        }
        __syncthreads();
    }

#pragma unroll
    for (int c = 0; c < 8; ++c) {
        int col = c * 16 + m;
#pragma unroll
        for (int r = 0; r < 4; ++r) {
            int row = row0 + quad * 4 + r;
            OutC[(size_t)row * CH + col] = __float2half(acc[c][r]);
        }
    }
}

// ---------------------------------------------------------------- aggregation
// One wave per dst node, HW fp16, out fp32. 8-deep manual load prefetch;
// fmas retired strictly in j-order (R5/R8/R9: reorder -> 7.3e-4 fail).
// FUSED=1: Hres = relu(LN(agg+bias)) + Hres.  FUSED=0: Out = agg+bias.
// (R15 lesson: do NOT fuse pooling via direct atomics — 625-way per-word
// contention serialized the kernel to 346 us.)
template <int FUSED>
__launch_bounds__(256)
__global__ void agg_kernel(const __half* __restrict__ HW, const int* __restrict__ rowptr,
                           const int* __restrict__ srcs, const float* __restrict__ isq,
                           const float* __restrict__ bias, const float* __restrict__ gamma,
                           const float* __restrict__ beta, float* __restrict__ Hres,
                           float* __restrict__ Out) {
    const int lane = threadIdx.x & 63;
    const int node = blockIdx.x * 4 + (threadIdx.x >> 6);
    const int start = rowptr[node];
    const int end = rowptr[node + 1];

    float ax = 0.f, ay = 0.f;
    for (int base = start; base < end; base += 64) {
        int idx = base + lane;
        int clamped = (idx < end) ? idx : (end - 1);
        int sl = srcs[clamped];
        float wl = isq[sl];
        int cnt = end - base;
        if (cnt > 64) cnt = 64;
        int j = 0;
        for (; j + 8 <= cnt; j += 8) {
            int s[8];
            float w[8];
            float2 v[8];
#pragma unroll
            for (int q = 0; q < 8; ++q) {
                s[q] = __shfl(sl, j + q);
                w[q] = __shfl(wl, j + q);
            }
#pragma unroll
            for (int q = 0; q < 8; ++q)
                v[q] = __half22float2(*(const __half2*)(HW + (size_t)s[q] * CH + lane * 2));
#pragma unroll
            for (int q = 0; q < 8; ++q) {
                ax = fmaf(w[q], v[q].x, ax);
                ay = fmaf(w[q], v[q].y, ay);
            }
        }
        for (; j + 4 <= cnt; j += 4) {
            int s0 = __shfl(sl, j), s1 = __shfl(sl, j + 1);
            int s2 = __shfl(sl, j + 2), s3 = __shfl(sl, j + 3);
            float w0 = __shfl(wl, j), w1 = __shfl(wl, j + 1);
            float w2 = __shfl(wl, j + 2), w3 = __shfl(wl, j + 3);
            float2 v0 = __half22float2(*(const __half2*)(HW + (size_t)s0 * CH + lane * 2));
            float2 v1 = __half22float2(*(const __half2*)(HW + (size_t)s1 * CH + lane * 2));
            float2 v2 = __half22float2(*(const __half2*)(HW + (size_t)s2 * CH + lane * 2));
            float2 v3 = __half22float2(*(const __half2*)(HW + (size_t)s3 * CH + lane * 2));
            ax = fmaf(w0, v0.x, ax); ay = fmaf(w0, v0.y, ay);
            ax = fmaf(w1, v1.x, ax); ay = fmaf(w1, v1.y, ay);
            ax = fmaf(w2, v2.x, ax); ay = fmaf(w2, v2.y, ay);
            ax = fmaf(w3, v3.x, ax); ay = fmaf(w3, v3.y, ay);
        }
        for (; j < cnt; ++j) {
            int s = __shfl(sl, j);
            float w = __shfl(wl, j);
            float2 vf = __half22float2(*(const __half2*)(HW + (size_t)s * CH + lane * 2));
            ax = fmaf(w, vf.x, ax);
            ay = fmaf(w, vf.y, ay);
        }
    }
    float d = isq[node];
    const __half2 hv = *(const __half2*)(HW + (size_t)node * CH + lane * 2);
    float2 hf = __half22float2(hv);
    const float2 bb = *(const float2*)(bias + lane * 2);
    float hx = d * ax + d * d * hf.x + bb.x;
    float hy = d * ay + d * d * hf.y + bb.y;

    if (!FUSED) {
        float2 o; o.x = hx; o.y = hy;
        *(float2*)(Out + (size_t)node * CH + lane * 2) = o;
        return;
    }
    float sum = hx + hy;
    float sq = hx * hx + hy * hy;
    for (int msk = 1; msk < 64; msk <<= 1) {
        sum += __shfl_xor(sum, msk);
        sq += __shfl_xor(sq, msk);
    }
    float mean = sum * (1.f / CH);
    float var = sq * (1.f / CH) - mean * mean;
    float rstd = rsqrtf(var + LN_EPS);
    const float2 gg = *(const float2*)(gamma + lane * 2);
    const float2 be = *(const float2*)(beta + lane * 2);
    float y0 = (hx - mean) * rstd * gg.x + be.x;
    float y1 = (hy - mean) * rstd * gg.y + be.y;
    float2* hp = (float2*)(Hres + (size_t)node * CH + lane * 2);
    float2 rr = *hp;
    float2 o;
    o.x = fmaxf(y0, 0.f) + rr.x;
    o.y = fmaxf(y1, 0.f) + rr.y;
    *hp = o;
}

// ---------------------------------------------------------------- pooling
// batch is sorted; each wave sums a 16-node strip, flushing atomics per run
// (run-length compression keeps atomic traffic ~1 add/word/wave-strip).
__launch_bounds__(256)
__global__ void pool_kernel(const float* __restrict__ H, const int* __restrict__ batch,
                            float* __restrict__ g, float* __restrict__ cntf) {
    const int lane = threadIdx.x & 63;
    const int w = blockIdx.x * 4 + (threadIdx.x >> 6);
    const int n0 = w * 16;
    float lx = 0.f, ly = 0.f;
    int run = 0;
    int cur = batch[n0];
    for (int t = 0; t < 16; ++t) {
        int n = n0 + t;
        int b = batch[n];
        if (b != cur) {
            atomicAdd(&g[(size_t)cur * CH + lane * 2], lx);
            atomicAdd(&g[(size_t)cur * CH + lane * 2 + 1], ly);
            if (lane == 0) atomicAdd(&cntf[cur], (float)run);
            lx = ly = 0.f; run = 0; cur = b;
        }
        const float2 v = *(const float2*)(H + (size_t)n * CH + lane * 2);
        lx += v.x; ly += v.y; ++run;
    }
    atomicAdd(&g[(size_t)cur * CH + lane * 2], lx);
    atomicAdd(&g[(size_t)cur * CH + lane * 2 + 1], ly);
    if (lane == 0) atomicAdd(&cntf[cur], (float)run);
}

// ---------------------------------------------------------------- classifier
__launch_bounds__(128)
__global__ void cls_kernel(const float* __restrict__ g, const float* __restrict__ cntf,
                           const float* __restrict__ w1, const float* __restrict__ b1,
                           const float* __restrict__ w2, const float* __restrict__ b2,
                           float* __restrict__ out) {
    __shared__ float gm[CH];
    __shared__ float red[2];
    const int b = blockIdx.x;
    const int t = threadIdx.x;
    float inv = 1.f / fmaxf(cntf[b], 1.f);
    gm[t] = g[(size_t)b * CH + t] * inv;
    __syncthreads();
    float acc = b1[t];
    for (int k = 0; k < CH; ++k) acc = fmaf(gm[k], w1[(size_t)k * CH + t], acc);
    float v = fmaxf(acc, 0.f) * w2[t];
    for (int msk = 1; msk < 64; msk <<= 1) v += __shfl_xor(v, msk);
    if ((t & 63) == 0) red[t >> 6] = v;
    __syncthreads();
    if (t == 0) out[b] = red[0] + red[1] + b2[0];
}

// ---------------------------------------------------------------- launch

extern "C" void kernel_launch(void* const* d_in, const int* in_sizes, int n_in,
                              void* d_out, int out_size, void* d_ws, size_t ws_size,
                              hipStream_t stream) {
    const float* x      = (const float*)d_in[0];
    const int*   ei     = (const int*)d_in[1];
    const int*   batch  = (const int*)d_in[2];
    const float* pre_w  = (const float*)d_in[3];
    const float* pre_b  = (const float*)d_in[4];
    const float* conv_w = (const float*)d_in[5];
    const float* conv_b = (const float*)d_in[6];
    const float* ln_g   = (const float*)d_in[7];
    const float* ln_b   = (const float*)d_in[8];
    const float* ffn_w1 = (const float*)d_in[9];
    const float* ffn_b1 = (const float*)d_in[10];
    const float* ffn_w2 = (const float*)d_in[11];
    const float* ffn_b2 = (const float*)d_in[12];
    const float* fln_g  = (const float*)d_in[13];
    const float* fln_b  = (const float*)d_in[14];
    const float* cls_w1 = (const float*)d_in[15];
    const float* cls_b1 = (const float*)d_in[16];
    const float* cls_w2 = (const float*)d_in[17];
    const float* cls_b2 = (const float*)d_in[18];

    float* H    = (float*)d_ws;                       // 40000*128 f32 (residual)
    float* T    = H + (size_t)N_NODES * CH;           // f32 (final agg out)
    float* R    = T + (size_t)N_NODES * CH;           // scratch
    __half* HWh = (__half*)R;                         // conv out fp16 (alias)
    int*   degi = (int*)(R + (size_t)N_NODES * CH);
    int*   fill = degi + N_NODES;
    float* g    = (float*)(fill + N_NODES);           // zero zone contiguous
    float* cntf = g + (size_t)NB * CH;
    float* isq  = cntf + NB;
    int*  rowptr = (int*)(isq + N_NODES);
    int*  bsum   = rowptr + N_NODES + 1;
    int*  boff   = bsum + 256;
    int*  srcs   = boff + 256;
    short* wpk   = (short*)(srcs + N_EDGES);          // 8 x 32768 shorts

    const int nb_scan = (N_NODES + 255) / 256;  // 157

    hipMemsetAsync(degi, 0, (size_t)(2 * N_NODES + NB * CH + NB) * sizeof(int), stream);

    deg_kernel<<<N_EDGES / 256, 256, 0, stream>>>(ei, degi);
    scan1_kernel<<<nb_scan, 256, 0, stream>>>(degi, rowptr, bsum, isq);
    scan2_kernel<<<1, 256, 0, stream>>>(bsum, boff, nb_scan);
    scan3_kernel<<<nb_scan, 256, 0, stream>>>(rowptr, boff);
    fill_csr_kernel<<<N_EDGES / 256, 256, 0, stream>>>(ei, rowptr, fill, srcs);
    pack_w_kernel<<<8 * 16384 / 256, 256, 0, stream>>>(pre_w, conv_w, ffn_w1, ffn_w2, wpk);

    const int gblk = N_NODES / 64;   // 625 (exact)
    const int lblk = N_NODES / 4;    // 10000

    // fused pre-scaler + conv0: H = x@pre_w+pre_b, HWh = fp16(H@conv_w0)
    gemm_fused<0><<<gblk, 256, 0, stream>>>(x, wpk, pre_b,
                                            wpk + 1 * 32768, nullptr, nullptr,
                                            nullptr, nullptr, nullptr, H, HWh);

    for (int i = 0; i < NL; ++i) {
        if (i < NL - 1) {
            // H = relu(LN(agg(HWh)+conv_b)) + H   (fused)
            agg_kernel<1><<<lblk, 256, 0, stream>>>(HWh, rowptr, srcs, isq,
                                                    conv_b + (size_t)i * CH,
                                                    ln_g + (size_t)i * CH,
                                                    ln_b + (size_t)i * CH, H, nullptr);
            // H = LN(relu(H@w1+b1)@w2+b2+H); HWh = fp16(H@conv_w[i+1])  (triple-fused)
            gemm_fused<1><<<gblk, 256, 0, stream>>>(H, wpk + (size_t)(4 + i) * 32768,
                                                    ffn_b1 + (size_t)i * CH,
                                                    wpk + (size_t)(6 + i) * 32768,
                                                    ffn_b2 + (size_t)i * CH, H,
                                                    fln_g + (size_t)i * CH,
                                                    fln_b + (size_t)i * CH,
                                                    wpk + (size_t)(2 + i) * 32768,
                                                    H, HWh);
        } else {
            // T = agg(HWh) + conv_b   (fp32)
            agg_kernel<0><<<lblk, 256, 0, stream>>>(HWh, rowptr, srcs, isq,
                                                    conv_b + (size_t)i * CH,
                                                    nullptr, nullptr, nullptr, T);
        }
    }

    pool_kernel<<<N_NODES / 64, 256, 0, stream>>>(T, batch, g, cntf);
    cls_kernel<<<NB, CH, 0, stream>>>(g, cntf, cls_w1, cls_b1, cls_w2, cls_b2,
                                      (float*)d_out);
}